// Round 7
// baseline (505.664 us; speedup 1.0000x reference)
//
#include <hip/hip_runtime.h>

#define NN 50000
#define HECNT 10000
#define EE 800000
#define II 800000
#define NBK 128          // buckets per task (counting sort)
#define CHUNK 4096       // edges per workgroup in bin
#define BKCAP 8192       // fixed staging capacity per bucket
#define BCSTRIDE 32      // bcur padding: one counter per 128B cacheline
#define BIN_GRID ((EE + CHUNK - 1) / CHUNK)   // 196

typedef _Float16 half8 __attribute__((ext_vector_type(8)));
typedef float f32x4    __attribute__((ext_vector_type(4)));
typedef unsigned short u16;

__device__ __forceinline__ void task_info(int t, int& n, int& cbase, int& obase) {
    if (t == 0)      { n = HECNT; cbase = 0;           obase = 0; }
    else if (t == 1) { n = NN;    cbase = HECNT;       obase = HECNT + 1; }
    else             { n = NN;    cbase = HECNT + NN;  obase = HECNT + NN + 2; }
}

// ---------------- one-time prep: weight frag layout + detect + bucket cursor init ----------------
__global__ __launch_bounds__(256) void prep_k(const int* __restrict__ EIX, const int* __restrict__ HIX,
                                              int* __restrict__ flags, int* __restrict__ bcur,
                                              const float* __restrict__ hc1_w, const float* __restrict__ lin1_w,
                                              const float* __restrict__ hc2_w, const float* __restrict__ lin2_w,
                                              const float* __restrict__ c1_wrel, const float* __restrict__ c1_wroot,
                                              const float* __restrict__ glin1_w,
                                              const float* __restrict__ c2_wrel, const float* __restrict__ c2_wroot,
                                              const float* __restrict__ glin2_w,
                                              const float* __restrict__ fc_w,
                                              _Float16* __restrict__ F) {
    int set = blockIdx.y;
    int tid = threadIdx.x;
    if (set == 5) {
        if (blockIdx.x != 0) return;
        for (int i = tid; i < 3 * NBK; i += 256) bcur[i * BCSTRIDE] = i * BKCAP;
        __shared__ int o0, o1;
        if (tid == 0) { o0 = 0; o1 = 0; }
        __syncthreads();
        atomicOr(&o0, EIX[2 * tid + 1]);
        atomicOr(&o1, HIX[2 * tid + 1]);
        __syncthreads();
        if (tid == 0) { flags[0] = (o0 == 0); flags[1] = (o1 == 0); }
        return;
    }
    int nfrag = (set == 4) ? 1024 : 4096;
    int NT = (set < 2) ? 16 : (set == 4 ? 4 : 8);
    int fid = blockIdx.x * 256 + tid;
    if (fid >= nfrag) return;
    int lane = fid & 63;
    int tile = fid >> 6;
    int nt = tile % NT, ks = tile / NT;
    int n = nt * 16 + (lane & 15);
    int kbase = ks * 32 + (lane >> 4) * 8;
    _Float16* dst = F + (size_t)set * 32768 + (size_t)fid * 8;
    #pragma unroll
    for (int j = 0; j < 8; j++) {
        int k = kbase + j;
        float w;
        if (set == 0)      w = (n < 128) ? hc1_w[k * 128 + n] : lin1_w[k * 128 + n - 128];
        else if (set == 1) w = (n < 128) ? hc2_w[k * 128 + n] : lin2_w[k * 128 + n - 128];
        else if (set == 2) w = (k < 128) ? c1_wrel[k * 128 + n]
                                         : c1_wroot[(k - 128) * 128 + n] + glin1_w[(k - 128) * 128 + n];
        else if (set == 3) w = (k < 128) ? c2_wrel[k * 128 + n]
                                         : c2_wroot[(k - 128) * 128 + n] + glin2_w[(k - 128) * 128 + n];
        else               w = fc_w[k * 64 + n];
        dst[j] = (_Float16)w;
    }
}

// ---- HIX dual-task bin: one load pass feeds BOTH task-0 (he<-node) and task-1 (node<-he) buckets ----
__device__ void bin_hix(int bx,
                        const int* __restrict__ HIX,
                        const int* __restrict__ flags, int* __restrict__ bcur,
                        unsigned* __restrict__ pairs) {
    __shared__ int hcnt[2][NBK], hrun[2][NBK], gbase[2][NBK];   // 3 KB
    int tid = threadIdx.x;
    const int span0 = (HECNT + NBK - 1) / NBK;   // 79
    const int span1 = (NN + NBK - 1) / NBK;      // 391
    long long base = (long long)bx * CHUNK;
    int f = flags[1];
    int mul = f ? 2 : 1;
    const int* narr = HIX;                               // node row
    const int* harr = HIX + (size_t)mul * 800000;        // hyperedge row

    for (int i = tid; i < NBK; i += 256) {
        hcnt[0][i] = 0; hrun[0][i] = 0;
        hcnt[1][i] = 0; hrun[1][i] = 0;
    }
    __syncthreads();

    int nd[16], he[16];
    #pragma unroll
    for (int jj = 0; jj < 8; jj++) {
        long long i = base + jj * 512 + tid * 2;
        int n0 = -1, n1 = -1, h0 = -1, h1 = -1;
        if (i < II) {
            if (f) {
                int4 nw = *(const int4*)(narr + 2 * i);
                int4 hw = *(const int4*)(harr + 2 * i);
                n0 = nw.x; n1 = nw.z; h0 = hw.x; h1 = hw.z;
            } else {
                int2 nw = *(const int2*)(narr + i);
                int2 hw = *(const int2*)(harr + i);
                n0 = nw.x; n1 = nw.y; h0 = hw.x; h1 = hw.y;
            }
        }
        nd[2 * jj] = n0; he[2 * jj] = h0;
        nd[2 * jj + 1] = n1; he[2 * jj + 1] = h1;
        if ((unsigned)h0 < (unsigned)HECNT && (unsigned)n0 < 65536u) atomicAdd(&hcnt[0][h0 / span0], 1);
        if ((unsigned)h1 < (unsigned)HECNT && (unsigned)n1 < 65536u) atomicAdd(&hcnt[0][h1 / span0], 1);
        if ((unsigned)n0 < (unsigned)NN && (unsigned)h0 < 65536u) atomicAdd(&hcnt[1][n0 / span1], 1);
        if ((unsigned)n1 < (unsigned)NN && (unsigned)h1 < 65536u) atomicAdd(&hcnt[1][n1 / span1], 1);
    }
    __syncthreads();

    if (tid < NBK) {
        int c = hcnt[0][tid];
        gbase[0][tid] = c ? atomicAdd(&bcur[tid * BCSTRIDE], c) : 0;
    } else if (tid < 2 * NBK) {
        int b = tid - NBK;
        int c = hcnt[1][b];
        gbase[1][b] = c ? atomicAdd(&bcur[(NBK + b) * BCSTRIDE], c) : 0;
    }
    __syncthreads();

    #pragma unroll
    for (int j = 0; j < 16; j++) {
        int n = nd[j], h = he[j];
        if ((unsigned)h < (unsigned)HECNT && (unsigned)n < 65536u) {
            int b = h / span0;
            int p = gbase[0][b] + atomicAdd(&hrun[0][b], 1);
            if (p < (b + 1) * BKCAP)
                pairs[p] = ((unsigned)h << 16) | (unsigned)n;
        }
        if ((unsigned)n < (unsigned)NN && (unsigned)h < 65536u) {
            int b = n / span1;
            int p = gbase[1][b] + atomicAdd(&hrun[1][b], 1);
            if (p < (NBK + b + 1) * BKCAP)
                pairs[p] = ((unsigned)n << 16) | (unsigned)h;
        }
    }
}

// ---- EIX task-2 bin: direct-scatter counting bin ----
__device__ void bin_eix(int bx,
                        const int* __restrict__ EIX,
                        const int* __restrict__ flags, int* __restrict__ bcur,
                        unsigned* __restrict__ pairs) {
    __shared__ int hcnt[NBK], hrun[NBK], gbase[NBK];   // 1.5 KB
    int tid = threadIdx.x;
    const int span = (NN + NBK - 1) / NBK;             // 391
    long long base = (long long)bx * CHUNK;
    int f = flags[0];
    int mul = f ? 2 : 1;
    const int* darr = EIX + (size_t)mul * 800000;      // dst row
    const int* varr = EIX;                             // src row

    for (int i = tid; i < NBK; i += 256) { hcnt[i] = 0; hrun[i] = 0; }
    __syncthreads();

    int d[16], v[16];
    #pragma unroll
    for (int jj = 0; jj < 8; jj++) {
        long long i = base + jj * 512 + tid * 2;
        int d0 = -1, d1 = -1, v0 = 0, v1 = 0;
        if (i < EE) {
            if (f) {
                int4 dw = *(const int4*)(darr + 2 * i);
                int4 vw = *(const int4*)(varr + 2 * i);
                d0 = dw.x; d1 = dw.z; v0 = vw.x; v1 = vw.z;
            } else {
                int2 dw = *(const int2*)(darr + i);
                int2 vw = *(const int2*)(varr + i);
                d0 = dw.x; d1 = dw.y; v0 = vw.x; v1 = vw.y;
            }
            if ((unsigned)d0 >= (unsigned)NN || (unsigned)v0 >= 65536u) d0 = -1;
            if ((unsigned)d1 >= (unsigned)NN || (unsigned)v1 >= 65536u) d1 = -1;
        }
        d[2 * jj] = d0; v[2 * jj] = v0;
        d[2 * jj + 1] = d1; v[2 * jj + 1] = v1;
        if (d0 >= 0) atomicAdd(&hcnt[d0 / span], 1);
        if (d1 >= 0) atomicAdd(&hcnt[d1 / span], 1);
    }
    __syncthreads();

    if (tid < NBK) gbase[tid] = hcnt[tid] ? atomicAdd(&bcur[(2 * NBK + tid) * BCSTRIDE], hcnt[tid]) : 0;
    __syncthreads();

    #pragma unroll
    for (int j = 0; j < 16; j++) {
        if (d[j] >= 0) {
            int b = d[j] / span;
            int p = gbase[b] + atomicAdd(&hrun[b], 1);
            if (p < (2 * NBK + b + 1) * BKCAP)
                pairs[p] = ((unsigned)d[j] << 16) | (unsigned)v[j];
        }
    }
}

// ---- dual-output GEMM from f32 global A, B-frags staged in LDS (bypass L1 BW wall) ----
__device__ void gemm2_f32(int bx, const float* __restrict__ A,
                          const half8* __restrict__ Bf,
                          const float* __restrict__ b2,
                          _Float16* __restrict__ O1, _Float16* __restrict__ O2, int M) {
    __shared__ __align__(16) half8 sB[4096];   // 64 KB
    constexpr int K = 128, NT = 16;
    int tid = threadIdx.x;
    #pragma unroll
    for (int i = 0; i < 16; i++) sB[tid + i * 256] = Bf[tid + i * 256];
    __syncthreads();

    int wave = tid >> 6, lane = tid & 63;
    int quad = lane >> 4, l16 = lane & 15;
    int rowbase = bx * 64 + wave * 16;
    int row = rowbase + l16;

    f32x4 acc[NT];
    f32x4 zero4 = {0.f, 0.f, 0.f, 0.f};
    #pragma unroll
    for (int nt = 0; nt < NT; nt++) acc[nt] = zero4;

    #pragma unroll
    for (int ks = 0; ks < 4; ks++) {
        int k0 = ks * 32 + quad * 8;
        half8 af = {0, 0, 0, 0, 0, 0, 0, 0};
        if (row < M) {
            const float* ap = A + (size_t)row * K + k0;
            float4 x0 = *(const float4*)ap;
            float4 x1 = *(const float4*)(ap + 4);
            af = half8{(_Float16)x0.x, (_Float16)x0.y, (_Float16)x0.z, (_Float16)x0.w,
                       (_Float16)x1.x, (_Float16)x1.y, (_Float16)x1.z, (_Float16)x1.w};
        }
        #pragma unroll
        for (int nt = 0; nt < NT; nt++) {
            half8 bfr = sB[(ks * NT + nt) * 64 + lane];
            acc[nt] = __builtin_amdgcn_mfma_f32_16x16x32_f16(af, bfr, acc[nt], 0, 0, 0);
        }
    }

    #pragma unroll
    for (int nt = 0; nt < NT; nt++) {
        int col = nt * 16 + l16;
        bool second = (col >= 128);
        int c = second ? col - 128 : col;
        float bv = second ? b2[c] : 0.f;
        _Float16* O = second ? O2 : O1;
        #pragma unroll
        for (int r = 0; r < 4; r++) {
            int rr = rowbase + quad * 4 + r;
            if (rr < M) O[(size_t)rr * 128 + c] = (_Float16)(acc[nt][r] + bv);
        }
    }
}

// ---------------- phase1: bin (HIX dual + EIX) + L1 GEMM run concurrently ----------------
__global__ __launch_bounds__(256) void phase1_k(const int* __restrict__ EIX, const int* __restrict__ HIX,
                                                const int* __restrict__ flags, int* __restrict__ bcur,
                                                unsigned* __restrict__ pairs,
                                                const float* __restrict__ X, const half8* __restrict__ F0,
                                                const float* __restrict__ lin1_b,
                                                _Float16* __restrict__ P, _Float16* __restrict__ L) {
    int bx = blockIdx.x;
    if (bx < BIN_GRID) {
        bin_hix(bx, HIX, flags, bcur, pairs);
    } else if (bx < 2 * BIN_GRID) {
        bin_eix(bx - BIN_GRID, EIX, flags, bcur, pairs);
    } else {
        gemm2_f32(bx - 2 * BIN_GRID, X, F0, lin1_b, P, L, NN);
    }
}

// ---------------- per-bucket finisher: shfl-based scans, exact placement, u16 flush ----------------
__global__ __launch_bounds__(256) void bfin2_k(const int* __restrict__ bcur,
                                               const unsigned* __restrict__ pairs,
                                               int* __restrict__ offs,
                                               u16* __restrict__ vals) {
    int idx = blockIdx.x;              // 0 .. 3*NBK-1
    int t = idx / NBK, b = idx % NBK;
    int n, cb, ob; task_info(t, n, cb, ob);
    int span = (n + NBK - 1) / NBK;
    int dlo = min(b * span, n), dhi = min(dlo + span, n);
    int tid = threadIdx.x;
    int lane = tid & 63, w = tid >> 6;

    __shared__ int scnt[NBK];
    __shared__ int wtot[2];
    {
        int s = 0;
        if (tid < NBK) {
            int c = bcur[(t * NBK + tid) * BCSTRIDE] - (t * NBK + tid) * BKCAP;
            s = max(0, min(c, BKCAP));
            #pragma unroll
            for (int o = 1; o < 64; o <<= 1) {
                int u = __shfl_up(s, o, 64);
                if (lane >= o) s += u;
            }
            if (lane == 63) wtot[w] = s;
        }
        __syncthreads();
        if (tid < NBK) {
            if (w == 1) s += wtot[0];
            scnt[tid] = s;
        }
        __syncthreads();
    }
    if (b == NBK - 1 && tid == 0) offs[ob + n] = scnt[NBK - 1];   // CSR sentinel
    if (dhi <= dlo) return;
    int nd = dhi - dlo;                // <= 391
    int base = (b > 0) ? scnt[b - 1] : 0;
    int cnt = scnt[b] - base;

    __shared__ int hist[512], cur[512];
    __shared__ u16 win[BKCAP];         // 16 KB
    __shared__ int wsum[4];
    for (int i = tid; i < 512; i += 256) hist[i] = 0;
    __syncthreads();

    const unsigned* pw = pairs + (size_t)idx * BKCAP;
    for (int i = tid; i < cnt; i += 256) {
        int dl = (int)(pw[i] >> 16) - dlo;
        if ((unsigned)dl < (unsigned)nd) atomicAdd(&hist[dl], 1);
    }
    __syncthreads();

    int i0 = 2 * tid, i1 = 2 * tid + 1;
    int ha = hist[i0], hb = hist[i1];
    int s = ha + hb;
    #pragma unroll
    for (int o = 1; o < 64; o <<= 1) {
        int u = __shfl_up(s, o, 64);
        if (lane >= o) s += u;
    }
    if (lane == 63) wsum[w] = s;
    __syncthreads();
    int woff = 0;
    #pragma unroll
    for (int k = 0; k < 4; k++) woff += (k < w) ? wsum[k] : 0;
    int incl1 = woff + s;
    int incl0 = incl1 - hb;
    if (i0 < nd) { int ex = incl0 - ha; offs[ob + dlo + i0] = base + ex; cur[i0] = ex; }
    if (i1 < nd) { int ex = incl1 - hb; offs[ob + dlo + i1] = base + ex; cur[i1] = ex; }
    __syncthreads();

    for (int i = tid; i < cnt; i += 256) {
        unsigned pv = pw[i];
        int dl = (int)(pv >> 16) - dlo;
        if ((unsigned)dl < (unsigned)nd) {
            int p = atomicAdd(&cur[dl], 1);
            if ((unsigned)p < (unsigned)BKCAP) win[p] = (u16)(pv & 0xffffu);
        }
    }
    __syncthreads();
    u16* vw = vals + (size_t)t * 800000 + base;
    for (int i = tid; i < cnt; i += 256) vw[i] = win[i];
}

// ------- standard gather (L2-resident src): 1 dest/wave, 4 subs x 16 lanes x half8 -------
__global__ __launch_bounds__(256) void gather_k(const int* __restrict__ offs,
                                                const u16* __restrict__ vals,
                                                const _Float16* __restrict__ src,   // [S x 128] f16
                                                _Float16* __restrict__ out,         // [ndst x 128] f16
                                                int ndst, int nsrc, int scale_flag,
                                                const float* __restrict__ bias,
                                                const _Float16* __restrict__ addend,
                                                int act) {
    int wave = threadIdx.x >> 6, lane = threadIdx.x & 63;
    int sub = lane >> 4, l16 = lane & 15;
    int d = blockIdx.x * 4 + wave;
    if (d >= ndst) return;
    int beg = offs[d], end = offs[d + 1];
    int f = l16 * 8;
    float a[8] = {0.f, 0.f, 0.f, 0.f, 0.f, 0.f, 0.f, 0.f};
    auto acc_row = [&](int s) {
        if ((unsigned)s < (unsigned)nsrc) {
            half8 u = *(const half8*)(src + (size_t)s * 128 + f);
            #pragma unroll
            for (int j = 0; j < 8; j++) a[j] += (float)u[j];
        }
    };
    int e = beg + sub;
    for (; e + 28 < end; e += 32) {          // 8 rows in flight per sub
        int s0 = vals[e], s1 = vals[e + 4], s2 = vals[e + 8], s3 = vals[e + 12];
        int s4 = vals[e + 16], s5 = vals[e + 20], s6 = vals[e + 24], s7 = vals[e + 28];
        acc_row(s0); acc_row(s1); acc_row(s2); acc_row(s3);
        acc_row(s4); acc_row(s5); acc_row(s6); acc_row(s7);
    }
    for (; e + 12 < end; e += 16) {          // 4 rows in flight per sub
        int s0 = vals[e], s1 = vals[e + 4], s2 = vals[e + 8], s3 = vals[e + 12];
        acc_row(s0); acc_row(s1); acc_row(s2); acc_row(s3);
    }
    for (; e < end; e += 4) acc_row(vals[e]);
    #pragma unroll
    for (int j = 0; j < 8; j++) {
        a[j] += __shfl_xor(a[j], 16, 64);
        a[j] += __shfl_xor(a[j], 32, 64);
    }
    if (sub == 0) {
        if (scale_flag) {
            int c = end - beg;
            float iv = (c > 0) ? 1.f / (float)c : 0.f;
            #pragma unroll
            for (int j = 0; j < 8; j++) a[j] *= iv;
        }
        if (bias) {
            f32x4 b0 = *(const f32x4*)(bias + f);
            f32x4 b1 = *(const f32x4*)(bias + f + 4);
            #pragma unroll
            for (int j = 0; j < 4; j++) { a[j] += b0[j]; a[4 + j] += b1[j]; }
        }
        if (addend) {
            half8 u = *(const half8*)(addend + (size_t)d * 128 + f);
            #pragma unroll
            for (int j = 0; j < 8; j++) a[j] += (float)u[j];
        }
        if (act) {
            #pragma unroll
            for (int j = 0; j < 8; j++) a[j] = (a[j] >= 0.f) ? a[j] : 0.01f * a[j];
        }
        half8 o;
        #pragma unroll
        for (int j = 0; j < 8; j++) o[j] = (_Float16)a[j];
        *(half8*)(out + (size_t)d * 128 + f) = o;
    }
}

// ------- feature-sliced gather (large src): blockIdx.y = 32-feature slice -> 3.2 MB working
// ------- set fits per-XCD L2. 16 row-subs x 4 feature-lanes per wave; shfl reduce over subs. -------
__global__ __launch_bounds__(256) void gatherS_k(const int* __restrict__ offs,
                                                 const u16* __restrict__ vals,
                                                 const _Float16* __restrict__ src,   // [S x 128] f16
                                                 _Float16* __restrict__ out,         // [ndst x 128] f16
                                                 int ndst, int nsrc, int scale_flag,
                                                 const float* __restrict__ bias,
                                                 const _Float16* __restrict__ addend,
                                                 int act) {
    int wave = threadIdx.x >> 6, lane = threadIdx.x & 63;
    int sub = lane >> 2, l4 = lane & 3;       // 16 subs x 4 feature-lanes
    int d = blockIdx.x * 4 + wave;
    if (d >= ndst) return;
    int beg = offs[d], end = offs[d + 1];
    int f = blockIdx.y * 32 + l4 * 8;
    float a[8] = {0.f, 0.f, 0.f, 0.f, 0.f, 0.f, 0.f, 0.f};
    auto acc_row = [&](int s) {
        if ((unsigned)s < (unsigned)nsrc) {
            half8 u = *(const half8*)(src + (size_t)s * 128 + f);
            #pragma unroll
            for (int j = 0; j < 8; j++) a[j] += (float)u[j];
        }
    };
    int e = beg + sub;
    for (; e + 48 < end; e += 64) {          // 4 rows in flight per sub (64/wave)
        int s0 = vals[e], s1 = vals[e + 16], s2 = vals[e + 32], s3 = vals[e + 48];
        acc_row(s0); acc_row(s1); acc_row(s2); acc_row(s3);
    }
    for (; e < end; e += 16) acc_row(vals[e]);   // 16 rows in flight per wave
    #pragma unroll
    for (int j = 0; j < 8; j++) {
        a[j] += __shfl_xor(a[j], 4, 64);
        a[j] += __shfl_xor(a[j], 8, 64);
        a[j] += __shfl_xor(a[j], 16, 64);
        a[j] += __shfl_xor(a[j], 32, 64);
    }
    if (sub == 0) {
        if (scale_flag) {
            int c = end - beg;
            float iv = (c > 0) ? 1.f / (float)c : 0.f;
            #pragma unroll
            for (int j = 0; j < 8; j++) a[j] *= iv;
        }
        if (bias) {
            f32x4 b0 = *(const f32x4*)(bias + f);
            f32x4 b1 = *(const f32x4*)(bias + f + 4);
            #pragma unroll
            for (int j = 0; j < 4; j++) { a[j] += b0[j]; a[4 + j] += b1[j]; }
        }
        if (addend) {
            half8 u = *(const half8*)(addend + (size_t)d * 128 + f);
            #pragma unroll
            for (int j = 0; j < 8; j++) a[j] += (float)u[j];
        }
        if (act) {
            #pragma unroll
            for (int j = 0; j < 8; j++) a[j] = (a[j] >= 0.f) ? a[j] : 0.01f * a[j];
        }
        half8 o;
        #pragma unroll
        for (int j = 0; j < 8; j++) o[j] = (_Float16)a[j];
        *(half8*)(out + (size_t)d * 128 + f) = o;
    }
}

// ---- dual-output GEMM from f16 global A, B-frags staged in LDS: P = A@W1, L = A@W2 + b2 ----
__global__ __launch_bounds__(256) void gemm2h_k(const _Float16* __restrict__ A,
                                                const half8* __restrict__ Bf,   // KS=4, NT=16
                                                const float* __restrict__ b2,
                                                _Float16* __restrict__ O1,
                                                _Float16* __restrict__ O2,
                                                int M) {
    __shared__ __align__(16) half8 sB[4096];   // 64 KB
    constexpr int K = 128, NT = 16;
    int tid = threadIdx.x;
    #pragma unroll
    for (int i = 0; i < 16; i++) sB[tid + i * 256] = Bf[tid + i * 256];
    __syncthreads();

    int wave = tid >> 6, lane = tid & 63;
    int quad = lane >> 4, l16 = lane & 15;
    int rowbase = blockIdx.x * 64 + wave * 16;
    int row = rowbase + l16;

    f32x4 acc[NT];
    f32x4 zero4 = {0.f, 0.f, 0.f, 0.f};
    #pragma unroll
    for (int nt = 0; nt < NT; nt++) acc[nt] = zero4;

    #pragma unroll
    for (int ks = 0; ks < 4; ks++) {
        int k0 = ks * 32 + quad * 8;
        half8 af = {0, 0, 0, 0, 0, 0, 0, 0};
        if (row < M) af = *(const half8*)(A + (size_t)row * K + k0);
        #pragma unroll
        for (int nt = 0; nt < NT; nt++) {
            half8 bfr = sB[(ks * NT + nt) * 64 + lane];
            acc[nt] = __builtin_amdgcn_mfma_f32_16x16x32_f16(af, bfr, acc[nt], 0, 0, 0);
        }
    }

    #pragma unroll
    for (int nt = 0; nt < NT; nt++) {
        int col = nt * 16 + l16;
        bool second = (col >= 128);
        int c = second ? col - 128 : col;
        float bv = second ? b2[c] : 0.f;
        _Float16* O = second ? O2 : O1;
        #pragma unroll
        for (int r = 0; r < 4; r++) {
            int rr = rowbase + quad * 4 + r;
            if (rr < M) O[(size_t)rr * 128 + c] = (_Float16)(acc[nt][r] + bv);
        }
    }
}

// ---- K=256 GEMM, B-frags staged in LDS: out = leaky(A0@Wrel + A1@(Wroot+Wlin) + brel + blin) ----
// FC=1: fc head on the result via LDS transpose. lt aliases the (dead) sB region, so a barrier
// separates the last sB read from the lt write.
template <int FC>
__global__ __launch_bounds__(256) void gemmk2_k(const _Float16* __restrict__ A0,
                                                const _Float16* A1,
                                                const half8* __restrict__ Bf,   // KS=8, NT=8
                                                const float* __restrict__ brel,
                                                const float* __restrict__ blin,
                                                float* __restrict__ Cf,    // f32 out (FC=1: final X)
                                                _Float16* Ch,              // f16 out (FC=0; may alias A1)
                                                const half8* __restrict__ Bfc,  // fc frags (FC=1)
                                                const float* __restrict__ bfc,
                                                float* __restrict__ Y,          // fc out (FC=1)
                                                int M) {
    constexpr int NFR = FC ? 5120 : 4096;
    __shared__ __align__(16) half8 sB[NFR];   // 80 KB (FC) / 64 KB
    constexpr int NT = 8;
    int tid = threadIdx.x;
    #pragma unroll
    for (int i = 0; i < 16; i++) sB[tid + i * 256] = Bf[tid + i * 256];
    if (FC) {
        #pragma unroll
        for (int i = 0; i < 4; i++) sB[4096 + tid + i * 256] = Bfc[tid + i * 256];
    }
    __syncthreads();

    int wave = tid >> 6, lane = tid & 63;
    int quad = lane >> 4, l16 = lane & 15;
    int rowbase = blockIdx.x * 64 + wave * 16;
    int row = rowbase + l16;

    f32x4 acc[NT];
    f32x4 zero4 = {0.f, 0.f, 0.f, 0.f};
    #pragma unroll
    for (int nt = 0; nt < NT; nt++) acc[nt] = zero4;

    #pragma unroll
    for (int ks = 0; ks < 8; ks++) {
        int k0 = ks * 32 + quad * 8;
        const _Float16* Asel = (k0 < 128) ? A0 : A1;
        int ka = k0 & 127;
        half8 af = {0, 0, 0, 0, 0, 0, 0, 0};
        if (row < M) af = *(const half8*)(Asel + (size_t)row * 128 + ka);
        #pragma unroll
        for (int nt = 0; nt < NT; nt++) {
            half8 bfr = sB[(ks * NT + nt) * 64 + lane];
            acc[nt] = __builtin_amdgcn_mfma_f32_16x16x32_f16(af, bfr, acc[nt], 0, 0, 0);
        }
    }

    _Float16* lt = (_Float16*)sB;      // FC only: reuse Bf region (17.4 KB < 64 KB)
    if (FC) __syncthreads();           // all sB reads complete before lt overwrite

    #pragma unroll
    for (int nt = 0; nt < NT; nt++) {
        int col = nt * 16 + l16;
        float bv = brel[col] + blin[col];
        #pragma unroll
        for (int r = 0; r < 4; r++) {
            int rr = rowbase + quad * 4 + r;
            float v = acc[nt][r] + bv;
            v = (v >= 0.f) ? v : 0.01f * v;
            if (rr < M) {
                if (FC) Cf[(size_t)rr * 128 + col] = v;
                else    Ch[(size_t)rr * 128 + col] = (_Float16)v;
            }
            if (FC) lt[(wave * 16 + quad * 4 + r) * 136 + col] = (_Float16)v;
        }
    }

    if (FC) {
        // fc head: Y = X4 @ fc_w + fc_b  (A-frags from band-local LDS tile, B-frags from sBfc)
        f32x4 a2[4];
        #pragma unroll
        for (int nt = 0; nt < 4; nt++) a2[nt] = zero4;
        #pragma unroll
        for (int ks = 0; ks < 4; ks++) {
            half8 af = *(const half8*)(lt + (wave * 16 + l16) * 136 + ks * 32 + quad * 8);
            #pragma unroll
            for (int nt = 0; nt < 4; nt++) {
                half8 bfr = sB[4096 + (ks * 4 + nt) * 64 + lane];
                a2[nt] = __builtin_amdgcn_mfma_f32_16x16x32_f16(af, bfr, a2[nt], 0, 0, 0);
            }
        }
        #pragma unroll
        for (int nt = 0; nt < 4; nt++) {
            int col = nt * 16 + l16;
            float bv = bfc[col];
            #pragma unroll
            for (int r = 0; r < 4; r++) {
                int rr = rowbase + quad * 4 + r;
                if (rr < M) Y[(size_t)rr * 64 + col] = a2[nt][r] + bv;
            }
        }
    }
}

extern "C" void kernel_launch(void* const* d_in, const int* in_sizes, int n_in,
                              void* d_out, int out_size, void* d_ws, size_t ws_size,
                              hipStream_t stream) {
    const float* X       = (const float*)d_in[0];
    const int*   EIX     = (const int*)d_in[1];
    const int*   HIX     = (const int*)d_in[2];
    const float* hc1_w   = (const float*)d_in[3];
    const float* hc1_b   = (const float*)d_in[4];
    const float* lin1_w  = (const float*)d_in[5];
    const float* lin1_b  = (const float*)d_in[6];
    const float* hc2_w   = (const float*)d_in[7];
    const float* hc2_b   = (const float*)d_in[8];
    const float* lin2_w  = (const float*)d_in[9];
    const float* lin2_b  = (const float*)d_in[10];
    const float* c1_wrel = (const float*)d_in[11];
    const float* c1_brel = (const float*)d_in[12];
    const float* c1_wroot= (const float*)d_in[13];
    const float* glin1_w = (const float*)d_in[14];
    const float* glin1_b = (const float*)d_in[15];
    const float* c2_wrel = (const float*)d_in[16];
    const float* c2_brel = (const float*)d_in[17];
    const float* c2_wroot= (const float*)d_in[18];
    const float* glin2_w = (const float*)d_in[19];
    const float* glin2_b = (const float*)d_in[20];
    const float* fc_w    = (const float*)d_in[21];
    const float* fc_b    = (const float*)d_in[22];

    // ---- workspace carve ----
    char* wsp = (char*)d_ws;
    size_t off = 0;
    auto carve = [&](size_t bytes) -> char* {
        char* p = wsp + off;
        off = (off + bytes + 255) & ~(size_t)255;
        return p;
    };
    int*   flags  = (int*)carve(16);
    int*   offs   = (int*)carve(110003 * 4);
    int*   bcur   = (int*)carve(3 * NBK * BCSTRIDE * 4);                  // 48 KB line-padded
    u16*   vals   = (u16*)carve(2400000 * 2);
    _Float16* F   = (_Float16*)carve((4 * 32768 + 8192) * 2);             // frag-ordered weights
    unsigned* pairs = (unsigned*)carve((size_t)3 * NBK * BKCAP * 4);      // 12.6 MB
    _Float16* P  = (_Float16*)carve((size_t)NN * 128 * 2);                // 12.8 MB
    _Float16* L  = (_Float16*)carve((size_t)NN * 128 * 2);                // 12.8 MB
    _Float16* MH = (_Float16*)carve((size_t)HECNT * 128 * 2);             // 2.56 MB
    _Float16* XA = (_Float16*)carve((size_t)NN * 128 * 2);                // 12.8 MB

    float* XO = (float*)d_out;                 // final X: 50000 x 128 f32
    float* YO = XO + (size_t)NN * 128;         // final y: 50000 x 64 f32

    const half8* F0 = (const half8*)F;                     // L1 [hc1|lin1]
    const half8* F1 = (const half8*)(F + 32768);           // L2
    const half8* F2 = (const half8*)(F + 2 * 32768);       // L3
    const half8* F3 = (const half8*)(F + 3 * 32768);       // L4
    const half8* F4 = (const half8*)(F + 4 * 32768);       // fc

    const int* offs_he   = offs;                    // [HECNT+1]
    const int* offs_node = offs + HECNT + 1;        // [NN+1]
    const int* offs_dst  = offs + HECNT + NN + 2;   // [NN+1]
    const u16* vals_he   = vals;
    const u16* vals_node = vals + 800000;
    const u16* vals_dst  = vals + 1600000;

    int g64 = (NN + 63) / 64;         // 782
    int ghe = (HECNT + 3) / 4;        // 2500
    int gnn = (NN + 3) / 4;           // 12500

    // 1. weight prep + detect + bucket cursor init
    prep_k<<<dim3(16, 6), 256, 0, stream>>>(EIX, HIX, flags, bcur,
                                            hc1_w, lin1_w, hc2_w, lin2_w,
                                            c1_wrel, c1_wroot, glin1_w,
                                            c2_wrel, c2_wroot, glin2_w, fc_w, F);
    // 2. bin (196 HIX-dual + 196 EIX blocks) || L1 GEMM (782 blocks)
    phase1_k<<<2 * BIN_GRID + g64, 256, 0, stream>>>(EIX, HIX, flags, bcur, pairs,
                                                     X, F0, lin1_b, P, L);
    // 3. CSR finish
    bfin2_k<<<3 * NBK, 256, 0, stream>>>(bcur, pairs, offs, vals);

    // ---- Layer 1: X1 = leaky(Dinv H Binv H^T (X@hc1) + hc1_b + X@lin1 + lin1_b) ----
    gatherS_k<<<dim3(ghe, 4), 256, 0, stream>>>(offs_he, vals_he, P, MH, HECNT, NN, 1, nullptr, nullptr, 0);
    gather_k<<<gnn, 256, 0, stream>>>(offs_node, vals_node, MH, XA, NN, HECNT, 1, hc1_b, L, 1);

    // ---- Layer 2 ----
    gemm2h_k<<<g64, 256, 0, stream>>>(XA, F1, lin2_b, P, L, NN);
    gatherS_k<<<dim3(ghe, 4), 256, 0, stream>>>(offs_he, vals_he, P, MH, HECNT, NN, 1, nullptr, nullptr, 0);
    gather_k<<<gnn, 256, 0, stream>>>(offs_node, vals_node, MH, XA, NN, HECNT, 1, hc2_b, L, 1);   // XA = X2

    // ---- Layer 3: X3 = leaky([AGG|X2] @ [Wrel; Wroot+glin1] + brel + glin1_b) ----
    gatherS_k<<<dim3(gnn, 4), 256, 0, stream>>>(offs_dst, vals_dst, XA, P, NN, NN, 0, nullptr, nullptr, 0); // P = AGG
    gemmk2_k<0><<<g64, 256, 0, stream>>>(P, XA, F2, c1_brel, glin1_b,
                                         nullptr, XA, nullptr, nullptr, nullptr, NN);             // XA = X3

    // ---- Layer 4 + fc head fused: AGG(X3) -> [AGG|X3] @ F3 -> XO (f32); X4 tile -> fc -> YO ----
    gatherS_k<<<dim3(gnn, 4), 256, 0, stream>>>(offs_dst, vals_dst, XA, P, NN, NN, 0, nullptr, nullptr, 0);
    gemmk2_k<1><<<g64, 256, 0, stream>>>(P, XA, F3, c2_brel, glin2_b,
                                         XO, nullptr, F4, fc_b, YO, NN);
}

// Round 8
// 430.882 us; speedup vs baseline: 1.1736x; 1.1736x over previous
//
#include <hip/hip_runtime.h>

#define NN 50000
#define HECNT 10000
#define EE 800000
#define II 800000
#define NBK 128          // buckets per task (counting sort)
#define CHUNK 4096       // edges per workgroup in bin
#define BKCAP 8192       // fixed staging capacity per bucket
#define BCSTRIDE 32      // bcur padding: one counter per 128B cacheline
#define BIN_GRID ((EE + CHUNK - 1) / CHUNK)   // 196

typedef _Float16 half8 __attribute__((ext_vector_type(8)));
typedef float f32x4    __attribute__((ext_vector_type(4)));
typedef unsigned short u16;

__device__ __forceinline__ void task_info(int t, int& n, int& cbase, int& obase) {
    if (t == 0)      { n = HECNT; cbase = 0;           obase = 0; }
    else if (t == 1) { n = NN;    cbase = HECNT;       obase = HECNT + 1; }
    else             { n = NN;    cbase = HECNT + NN;  obase = HECNT + NN + 2; }
}

// ---------------- one-time prep: weight frag layout + detect + bucket cursor init ----------------
__global__ __launch_bounds__(256) void prep_k(const int* __restrict__ EIX, const int* __restrict__ HIX,
                                              int* __restrict__ flags, int* __restrict__ bcur,
                                              const float* __restrict__ hc1_w, const float* __restrict__ lin1_w,
                                              const float* __restrict__ hc2_w, const float* __restrict__ lin2_w,
                                              const float* __restrict__ c1_wrel, const float* __restrict__ c1_wroot,
                                              const float* __restrict__ glin1_w,
                                              const float* __restrict__ c2_wrel, const float* __restrict__ c2_wroot,
                                              const float* __restrict__ glin2_w,
                                              const float* __restrict__ fc_w,
                                              _Float16* __restrict__ F) {
    int set = blockIdx.y;
    int tid = threadIdx.x;
    if (set == 5) {
        if (blockIdx.x != 0) return;
        for (int i = tid; i < 3 * NBK; i += 256) bcur[i * BCSTRIDE] = i * BKCAP;
        __shared__ int o0, o1;
        if (tid == 0) { o0 = 0; o1 = 0; }
        __syncthreads();
        atomicOr(&o0, EIX[2 * tid + 1]);
        atomicOr(&o1, HIX[2 * tid + 1]);
        __syncthreads();
        if (tid == 0) { flags[0] = (o0 == 0); flags[1] = (o1 == 0); }
        return;
    }
    int nfrag = (set == 4) ? 1024 : 4096;
    int NT = (set < 2) ? 16 : (set == 4 ? 4 : 8);
    int fid = blockIdx.x * 256 + tid;
    if (fid >= nfrag) return;
    int lane = fid & 63;
    int tile = fid >> 6;
    int nt = tile % NT, ks = tile / NT;
    int n = nt * 16 + (lane & 15);
    int kbase = ks * 32 + (lane >> 4) * 8;
    _Float16* dst = F + (size_t)set * 32768 + (size_t)fid * 8;
    #pragma unroll
    for (int j = 0; j < 8; j++) {
        int k = kbase + j;
        float w;
        if (set == 0)      w = (n < 128) ? hc1_w[k * 128 + n] : lin1_w[k * 128 + n - 128];
        else if (set == 1) w = (n < 128) ? hc2_w[k * 128 + n] : lin2_w[k * 128 + n - 128];
        else if (set == 2) w = (k < 128) ? c1_wrel[k * 128 + n]
                                         : c1_wroot[(k - 128) * 128 + n] + glin1_w[(k - 128) * 128 + n];
        else if (set == 3) w = (k < 128) ? c2_wrel[k * 128 + n]
                                         : c2_wroot[(k - 128) * 128 + n] + glin2_w[(k - 128) * 128 + n];
        else               w = fc_w[k * 64 + n];
        dst[j] = (_Float16)w;
    }
}

// ---- HIX dual-task bin: one load pass feeds BOTH task-0 (he<-node) and task-1 (node<-he) buckets ----
__device__ void bin_hix(int bx,
                        const int* __restrict__ HIX,
                        const int* __restrict__ flags, int* __restrict__ bcur,
                        unsigned* __restrict__ pairs) {
    __shared__ int hcnt[2][NBK], hrun[2][NBK], gbase[2][NBK];   // 3 KB
    int tid = threadIdx.x;
    const int span0 = (HECNT + NBK - 1) / NBK;   // 79
    const int span1 = (NN + NBK - 1) / NBK;      // 391
    long long base = (long long)bx * CHUNK;
    int f = flags[1];
    int mul = f ? 2 : 1;
    const int* narr = HIX;                               // node row
    const int* harr = HIX + (size_t)mul * 800000;        // hyperedge row

    for (int i = tid; i < NBK; i += 256) {
        hcnt[0][i] = 0; hrun[0][i] = 0;
        hcnt[1][i] = 0; hrun[1][i] = 0;
    }
    __syncthreads();

    int nd[16], he[16];
    #pragma unroll
    for (int jj = 0; jj < 8; jj++) {
        long long i = base + jj * 512 + tid * 2;
        int n0 = -1, n1 = -1, h0 = -1, h1 = -1;
        if (i < II) {
            if (f) {
                int4 nw = *(const int4*)(narr + 2 * i);
                int4 hw = *(const int4*)(harr + 2 * i);
                n0 = nw.x; n1 = nw.z; h0 = hw.x; h1 = hw.z;
            } else {
                int2 nw = *(const int2*)(narr + i);
                int2 hw = *(const int2*)(harr + i);
                n0 = nw.x; n1 = nw.y; h0 = hw.x; h1 = hw.y;
            }
        }
        nd[2 * jj] = n0; he[2 * jj] = h0;
        nd[2 * jj + 1] = n1; he[2 * jj + 1] = h1;
        if ((unsigned)h0 < (unsigned)HECNT && (unsigned)n0 < 65536u) atomicAdd(&hcnt[0][h0 / span0], 1);
        if ((unsigned)h1 < (unsigned)HECNT && (unsigned)n1 < 65536u) atomicAdd(&hcnt[0][h1 / span0], 1);
        if ((unsigned)n0 < (unsigned)NN && (unsigned)h0 < 65536u) atomicAdd(&hcnt[1][n0 / span1], 1);
        if ((unsigned)n1 < (unsigned)NN && (unsigned)h1 < 65536u) atomicAdd(&hcnt[1][n1 / span1], 1);
    }
    __syncthreads();

    if (tid < NBK) {
        int c = hcnt[0][tid];
        gbase[0][tid] = c ? atomicAdd(&bcur[tid * BCSTRIDE], c) : 0;
    } else if (tid < 2 * NBK) {
        int b = tid - NBK;
        int c = hcnt[1][b];
        gbase[1][b] = c ? atomicAdd(&bcur[(NBK + b) * BCSTRIDE], c) : 0;
    }
    __syncthreads();

    #pragma unroll
    for (int j = 0; j < 16; j++) {
        int n = nd[j], h = he[j];
        if ((unsigned)h < (unsigned)HECNT && (unsigned)n < 65536u) {
            int b = h / span0;
            int p = gbase[0][b] + atomicAdd(&hrun[0][b], 1);
            if (p < (b + 1) * BKCAP)
                pairs[p] = ((unsigned)h << 16) | (unsigned)n;
        }
        if ((unsigned)n < (unsigned)NN && (unsigned)h < 65536u) {
            int b = n / span1;
            int p = gbase[1][b] + atomicAdd(&hrun[1][b], 1);
            if (p < (NBK + b + 1) * BKCAP)
                pairs[p] = ((unsigned)n << 16) | (unsigned)h;
        }
    }
}

// ---- EIX task-2 bin: direct-scatter counting bin ----
__device__ void bin_eix(int bx,
                        const int* __restrict__ EIX,
                        const int* __restrict__ flags, int* __restrict__ bcur,
                        unsigned* __restrict__ pairs) {
    __shared__ int hcnt[NBK], hrun[NBK], gbase[NBK];   // 1.5 KB
    int tid = threadIdx.x;
    const int span = (NN + NBK - 1) / NBK;             // 391
    long long base = (long long)bx * CHUNK;
    int f = flags[0];
    int mul = f ? 2 : 1;
    const int* darr = EIX + (size_t)mul * 800000;      // dst row
    const int* varr = EIX;                             // src row

    for (int i = tid; i < NBK; i += 256) { hcnt[i] = 0; hrun[i] = 0; }
    __syncthreads();

    int d[16], v[16];
    #pragma unroll
    for (int jj = 0; jj < 8; jj++) {
        long long i = base + jj * 512 + tid * 2;
        int d0 = -1, d1 = -1, v0 = 0, v1 = 0;
        if (i < EE) {
            if (f) {
                int4 dw = *(const int4*)(darr + 2 * i);
                int4 vw = *(const int4*)(varr + 2 * i);
                d0 = dw.x; d1 = dw.z; v0 = vw.x; v1 = vw.z;
            } else {
                int2 dw = *(const int2*)(darr + i);
                int2 vw = *(const int2*)(varr + i);
                d0 = dw.x; d1 = dw.y; v0 = vw.x; v1 = vw.y;
            }
            if ((unsigned)d0 >= (unsigned)NN || (unsigned)v0 >= 65536u) d0 = -1;
            if ((unsigned)d1 >= (unsigned)NN || (unsigned)v1 >= 65536u) d1 = -1;
        }
        d[2 * jj] = d0; v[2 * jj] = v0;
        d[2 * jj + 1] = d1; v[2 * jj + 1] = v1;
        if (d0 >= 0) atomicAdd(&hcnt[d0 / span], 1);
        if (d1 >= 0) atomicAdd(&hcnt[d1 / span], 1);
    }
    __syncthreads();

    if (tid < NBK) gbase[tid] = hcnt[tid] ? atomicAdd(&bcur[(2 * NBK + tid) * BCSTRIDE], hcnt[tid]) : 0;
    __syncthreads();

    #pragma unroll
    for (int j = 0; j < 16; j++) {
        if (d[j] >= 0) {
            int b = d[j] / span;
            int p = gbase[b] + atomicAdd(&hrun[b], 1);
            if (p < (2 * NBK + b + 1) * BKCAP)
                pairs[p] = ((unsigned)d[j] << 16) | (unsigned)v[j];
        }
    }
}

// ---- dual-output GEMM from f32 global A, B-frags staged in LDS (bypass L1 BW wall) ----
__device__ void gemm2_f32(int bx, const float* __restrict__ A,
                          const half8* __restrict__ Bf,
                          const float* __restrict__ b2,
                          _Float16* __restrict__ O1, _Float16* __restrict__ O2, int M) {
    __shared__ __align__(16) half8 sB[4096];   // 64 KB
    constexpr int K = 128, NT = 16;
    int tid = threadIdx.x;
    #pragma unroll
    for (int i = 0; i < 16; i++) sB[tid + i * 256] = Bf[tid + i * 256];
    __syncthreads();

    int wave = tid >> 6, lane = tid & 63;
    int quad = lane >> 4, l16 = lane & 15;
    int rowbase = bx * 64 + wave * 16;
    int row = rowbase + l16;

    f32x4 acc[NT];
    f32x4 zero4 = {0.f, 0.f, 0.f, 0.f};
    #pragma unroll
    for (int nt = 0; nt < NT; nt++) acc[nt] = zero4;

    #pragma unroll
    for (int ks = 0; ks < 4; ks++) {
        int k0 = ks * 32 + quad * 8;
        half8 af = {0, 0, 0, 0, 0, 0, 0, 0};
        if (row < M) {
            const float* ap = A + (size_t)row * K + k0;
            float4 x0 = *(const float4*)ap;
            float4 x1 = *(const float4*)(ap + 4);
            af = half8{(_Float16)x0.x, (_Float16)x0.y, (_Float16)x0.z, (_Float16)x0.w,
                       (_Float16)x1.x, (_Float16)x1.y, (_Float16)x1.z, (_Float16)x1.w};
        }
        #pragma unroll
        for (int nt = 0; nt < NT; nt++) {
            half8 bfr = sB[(ks * NT + nt) * 64 + lane];
            acc[nt] = __builtin_amdgcn_mfma_f32_16x16x32_f16(af, bfr, acc[nt], 0, 0, 0);
        }
    }

    #pragma unroll
    for (int nt = 0; nt < NT; nt++) {
        int col = nt * 16 + l16;
        bool second = (col >= 128);
        int c = second ? col - 128 : col;
        float bv = second ? b2[c] : 0.f;
        _Float16* O = second ? O2 : O1;
        #pragma unroll
        for (int r = 0; r < 4; r++) {
            int rr = rowbase + quad * 4 + r;
            if (rr < M) O[(size_t)rr * 128 + c] = (_Float16)(acc[nt][r] + bv);
        }
    }
}

// ---------------- phase1: bin (HIX dual + EIX) + L1 GEMM run concurrently ----------------
__global__ __launch_bounds__(256) void phase1_k(const int* __restrict__ EIX, const int* __restrict__ HIX,
                                                const int* __restrict__ flags, int* __restrict__ bcur,
                                                unsigned* __restrict__ pairs,
                                                const float* __restrict__ X, const half8* __restrict__ F0,
                                                const float* __restrict__ lin1_b,
                                                _Float16* __restrict__ P, _Float16* __restrict__ L) {
    int bx = blockIdx.x;
    if (bx < BIN_GRID) {
        bin_hix(bx, HIX, flags, bcur, pairs);
    } else if (bx < 2 * BIN_GRID) {
        bin_eix(bx - BIN_GRID, EIX, flags, bcur, pairs);
    } else {
        gemm2_f32(bx - 2 * BIN_GRID, X, F0, lin1_b, P, L, NN);
    }
}

// ---------------- per-bucket finisher: shfl-based scans, exact placement, u16 flush ----------------
__global__ __launch_bounds__(256) void bfin2_k(const int* __restrict__ bcur,
                                               const unsigned* __restrict__ pairs,
                                               int* __restrict__ offs,
                                               u16* __restrict__ vals) {
    int idx = blockIdx.x;              // 0 .. 3*NBK-1
    int t = idx / NBK, b = idx % NBK;
    int n, cb, ob; task_info(t, n, cb, ob);
    int span = (n + NBK - 1) / NBK;
    int dlo = min(b * span, n), dhi = min(dlo + span, n);
    int tid = threadIdx.x;
    int lane = tid & 63, w = tid >> 6;

    __shared__ int scnt[NBK];
    __shared__ int wtot[2];
    {
        int s = 0;
        if (tid < NBK) {
            int c = bcur[(t * NBK + tid) * BCSTRIDE] - (t * NBK + tid) * BKCAP;
            s = max(0, min(c, BKCAP));
            #pragma unroll
            for (int o = 1; o < 64; o <<= 1) {
                int u = __shfl_up(s, o, 64);
                if (lane >= o) s += u;
            }
            if (lane == 63) wtot[w] = s;
        }
        __syncthreads();
        if (tid < NBK) {
            if (w == 1) s += wtot[0];
            scnt[tid] = s;
        }
        __syncthreads();
    }
    if (b == NBK - 1 && tid == 0) offs[ob + n] = scnt[NBK - 1];   // CSR sentinel
    if (dhi <= dlo) return;
    int nd = dhi - dlo;                // <= 391
    int base = (b > 0) ? scnt[b - 1] : 0;
    int cnt = scnt[b] - base;

    __shared__ int hist[512], cur[512];
    __shared__ u16 win[BKCAP];         // 16 KB
    __shared__ int wsum[4];
    for (int i = tid; i < 512; i += 256) hist[i] = 0;
    __syncthreads();

    const unsigned* pw = pairs + (size_t)idx * BKCAP;
    for (int i = tid; i < cnt; i += 256) {
        int dl = (int)(pw[i] >> 16) - dlo;
        if ((unsigned)dl < (unsigned)nd) atomicAdd(&hist[dl], 1);
    }
    __syncthreads();

    int i0 = 2 * tid, i1 = 2 * tid + 1;
    int ha = hist[i0], hb = hist[i1];
    int s = ha + hb;
    #pragma unroll
    for (int o = 1; o < 64; o <<= 1) {
        int u = __shfl_up(s, o, 64);
        if (lane >= o) s += u;
    }
    if (lane == 63) wsum[w] = s;
    __syncthreads();
    int woff = 0;
    #pragma unroll
    for (int k = 0; k < 4; k++) woff += (k < w) ? wsum[k] : 0;
    int incl1 = woff + s;
    int incl0 = incl1 - hb;
    if (i0 < nd) { int ex = incl0 - ha; offs[ob + dlo + i0] = base + ex; cur[i0] = ex; }
    if (i1 < nd) { int ex = incl1 - hb; offs[ob + dlo + i1] = base + ex; cur[i1] = ex; }
    __syncthreads();

    for (int i = tid; i < cnt; i += 256) {
        unsigned pv = pw[i];
        int dl = (int)(pv >> 16) - dlo;
        if ((unsigned)dl < (unsigned)nd) {
            int p = atomicAdd(&cur[dl], 1);
            if ((unsigned)p < (unsigned)BKCAP) win[p] = (u16)(pv & 0xffffu);
        }
    }
    __syncthreads();
    u16* vw = vals + (size_t)t * 800000 + base;
    for (int i = tid; i < cnt; i += 256) vw[i] = win[i];
}

// ------- standalone gather: 1 dest/wave (max TLP), 16 lanes x half8; 8-row-flight tier -------
__global__ __launch_bounds__(256) void gather_k(const int* __restrict__ offs,
                                                const u16* __restrict__ vals,
                                                const _Float16* __restrict__ src,   // [S x 128] f16
                                                _Float16* __restrict__ out,         // [ndst x 128] f16
                                                int ndst, int nsrc, int scale_flag,
                                                const float* __restrict__ bias,
                                                const _Float16* __restrict__ addend,
                                                int act) {
    int wave = threadIdx.x >> 6, lane = threadIdx.x & 63;
    int sub = lane >> 4, l16 = lane & 15;
    int d = blockIdx.x * 4 + wave;
    if (d >= ndst) return;
    int beg = offs[d], end = offs[d + 1];
    int f = l16 * 8;
    float a[8] = {0.f, 0.f, 0.f, 0.f, 0.f, 0.f, 0.f, 0.f};
    auto acc_row = [&](int s) {
        if ((unsigned)s < (unsigned)nsrc) {
            half8 u = *(const half8*)(src + (size_t)s * 128 + f);
            #pragma unroll
            for (int j = 0; j < 8; j++) a[j] += (float)u[j];
        }
    };
    int e = beg + sub;
    for (; e + 28 < end; e += 32) {          // 8 rows in flight per sub
        int s0 = vals[e], s1 = vals[e + 4], s2 = vals[e + 8], s3 = vals[e + 12];
        int s4 = vals[e + 16], s5 = vals[e + 20], s6 = vals[e + 24], s7 = vals[e + 28];
        acc_row(s0); acc_row(s1); acc_row(s2); acc_row(s3);
        acc_row(s4); acc_row(s5); acc_row(s6); acc_row(s7);
    }
    for (; e + 12 < end; e += 16) {          // 4 rows in flight per sub
        int s0 = vals[e], s1 = vals[e + 4], s2 = vals[e + 8], s3 = vals[e + 12];
        acc_row(s0); acc_row(s1); acc_row(s2); acc_row(s3);
    }
    for (; e < end; e += 4) acc_row(vals[e]);
    #pragma unroll
    for (int j = 0; j < 8; j++) {
        a[j] += __shfl_xor(a[j], 16, 64);
        a[j] += __shfl_xor(a[j], 32, 64);
    }
    if (sub == 0) {
        if (scale_flag) {
            int c = end - beg;
            float iv = (c > 0) ? 1.f / (float)c : 0.f;
            #pragma unroll
            for (int j = 0; j < 8; j++) a[j] *= iv;
        }
        if (bias) {
            f32x4 b0 = *(const f32x4*)(bias + f);
            f32x4 b1 = *(const f32x4*)(bias + f + 4);
            #pragma unroll
            for (int j = 0; j < 4; j++) { a[j] += b0[j]; a[4 + j] += b1[j]; }
        }
        if (addend) {
            half8 u = *(const half8*)(addend + (size_t)d * 128 + f);
            #pragma unroll
            for (int j = 0; j < 8; j++) a[j] += (float)u[j];
        }
        if (act) {
            #pragma unroll
            for (int j = 0; j < 8; j++) a[j] = (a[j] >= 0.f) ? a[j] : 0.01f * a[j];
        }
        half8 o;
        #pragma unroll
        for (int j = 0; j < 8; j++) o[j] = (_Float16)a[j];
        *(half8*)(out + (size_t)d * 128 + f) = o;
    }
}

// ---- dual-output GEMM from f16 global A, B-frags staged in LDS: P = A@W1, L = A@W2 + b2 ----
__global__ __launch_bounds__(256) void gemm2h_k(const _Float16* __restrict__ A,
                                                const half8* __restrict__ Bf,   // KS=4, NT=16
                                                const float* __restrict__ b2,
                                                _Float16* __restrict__ O1,
                                                _Float16* __restrict__ O2,
                                                int M) {
    __shared__ __align__(16) half8 sB[4096];   // 64 KB
    constexpr int K = 128, NT = 16;
    int tid = threadIdx.x;
    #pragma unroll
    for (int i = 0; i < 16; i++) sB[tid + i * 256] = Bf[tid + i * 256];
    __syncthreads();

    int wave = tid >> 6, lane = tid & 63;
    int quad = lane >> 4, l16 = lane & 15;
    int rowbase = blockIdx.x * 64 + wave * 16;
    int row = rowbase + l16;

    f32x4 acc[NT];
    f32x4 zero4 = {0.f, 0.f, 0.f, 0.f};
    #pragma unroll
    for (int nt = 0; nt < NT; nt++) acc[nt] = zero4;

    #pragma unroll
    for (int ks = 0; ks < 4; ks++) {
        int k0 = ks * 32 + quad * 8;
        half8 af = {0, 0, 0, 0, 0, 0, 0, 0};
        if (row < M) af = *(const half8*)(A + (size_t)row * K + k0);
        #pragma unroll
        for (int nt = 0; nt < NT; nt++) {
            half8 bfr = sB[(ks * NT + nt) * 64 + lane];
            acc[nt] = __builtin_amdgcn_mfma_f32_16x16x32_f16(af, bfr, acc[nt], 0, 0, 0);
        }
    }

    #pragma unroll
    for (int nt = 0; nt < NT; nt++) {
        int col = nt * 16 + l16;
        bool second = (col >= 128);
        int c = second ? col - 128 : col;
        float bv = second ? b2[c] : 0.f;
        _Float16* O = second ? O2 : O1;
        #pragma unroll
        for (int r = 0; r < 4; r++) {
            int rr = rowbase + quad * 4 + r;
            if (rr < M) O[(size_t)rr * 128 + c] = (_Float16)(acc[nt][r] + bv);
        }
    }
}

// ---- K=256 GEMM, B-frags staged in LDS: out = leaky(A0@Wrel + A1@(Wroot+Wlin) + brel + blin) ----
// FC=1: fc head on the result via LDS transpose. lt aliases the (dead) sB region, so a barrier
// separates the last sB read from the lt write.
template <int FC>
__global__ __launch_bounds__(256) void gemmk2_k(const _Float16* __restrict__ A0,
                                                const _Float16* A1,
                                                const half8* __restrict__ Bf,   // KS=8, NT=8
                                                const float* __restrict__ brel,
                                                const float* __restrict__ blin,
                                                float* __restrict__ Cf,    // f32 out (FC=1: final X)
                                                _Float16* Ch,              // f16 out (FC=0; may alias A1)
                                                const half8* __restrict__ Bfc,  // fc frags (FC=1)
                                                const float* __restrict__ bfc,
                                                float* __restrict__ Y,          // fc out (FC=1)
                                                int M) {
    constexpr int NFR = FC ? 5120 : 4096;
    __shared__ __align__(16) half8 sB[NFR];   // 80 KB (FC) / 64 KB
    constexpr int NT = 8;
    int tid = threadIdx.x;
    #pragma unroll
    for (int i = 0; i < 16; i++) sB[tid + i * 256] = Bf[tid + i * 256];
    if (FC) {
        #pragma unroll
        for (int i = 0; i < 4; i++) sB[4096 + tid + i * 256] = Bfc[tid + i * 256];
    }
    __syncthreads();

    int wave = tid >> 6, lane = tid & 63;
    int quad = lane >> 4, l16 = lane & 15;
    int rowbase = blockIdx.x * 64 + wave * 16;
    int row = rowbase + l16;

    f32x4 acc[NT];
    f32x4 zero4 = {0.f, 0.f, 0.f, 0.f};
    #pragma unroll
    for (int nt = 0; nt < NT; nt++) acc[nt] = zero4;

    #pragma unroll
    for (int ks = 0; ks < 8; ks++) {
        int k0 = ks * 32 + quad * 8;
        const _Float16* Asel = (k0 < 128) ? A0 : A1;
        int ka = k0 & 127;
        half8 af = {0, 0, 0, 0, 0, 0, 0, 0};
        if (row < M) af = *(const half8*)(Asel + (size_t)row * 128 + ka);
        #pragma unroll
        for (int nt = 0; nt < NT; nt++) {
            half8 bfr = sB[(ks * NT + nt) * 64 + lane];
            acc[nt] = __builtin_amdgcn_mfma_f32_16x16x32_f16(af, bfr, acc[nt], 0, 0, 0);
        }
    }

    _Float16* lt = (_Float16*)sB;      // FC only: reuse Bf region (17.4 KB < 64 KB)
    if (FC) __syncthreads();           // all sB reads complete before lt overwrite

    #pragma unroll
    for (int nt = 0; nt < NT; nt++) {
        int col = nt * 16 + l16;
        float bv = brel[col] + blin[col];
        #pragma unroll
        for (int r = 0; r < 4; r++) {
            int rr = rowbase + quad * 4 + r;
            float v = acc[nt][r] + bv;
            v = (v >= 0.f) ? v : 0.01f * v;
            if (rr < M) {
                if (FC) Cf[(size_t)rr * 128 + col] = v;
                else    Ch[(size_t)rr * 128 + col] = (_Float16)v;
            }
            if (FC) lt[(wave * 16 + quad * 4 + r) * 136 + col] = (_Float16)v;
        }
    }

    if (FC) {
        // fc head: Y = X4 @ fc_w + fc_b  (A-frags from band-local LDS tile, B-frags from sBfc)
        f32x4 a2[4];
        #pragma unroll
        for (int nt = 0; nt < 4; nt++) a2[nt] = zero4;
        #pragma unroll
        for (int ks = 0; ks < 4; ks++) {
            half8 af = *(const half8*)(lt + (wave * 16 + l16) * 136 + ks * 32 + quad * 8);
            #pragma unroll
            for (int nt = 0; nt < 4; nt++) {
                half8 bfr = sB[4096 + (ks * 4 + nt) * 64 + lane];
                a2[nt] = __builtin_amdgcn_mfma_f32_16x16x32_f16(af, bfr, a2[nt], 0, 0, 0);
            }
        }
        #pragma unroll
        for (int nt = 0; nt < 4; nt++) {
            int col = nt * 16 + l16;
            float bv = bfc[col];
            #pragma unroll
            for (int r = 0; r < 4; r++) {
                int rr = rowbase + quad * 4 + r;
                if (rr < M) Y[(size_t)rr * 64 + col] = a2[nt][r] + bv;
            }
        }
    }
}

extern "C" void kernel_launch(void* const* d_in, const int* in_sizes, int n_in,
                              void* d_out, int out_size, void* d_ws, size_t ws_size,
                              hipStream_t stream) {
    const float* X       = (const float*)d_in[0];
    const int*   EIX     = (const int*)d_in[1];
    const int*   HIX     = (const int*)d_in[2];
    const float* hc1_w   = (const float*)d_in[3];
    const float* hc1_b   = (const float*)d_in[4];
    const float* lin1_w  = (const float*)d_in[5];
    const float* lin1_b  = (const float*)d_in[6];
    const float* hc2_w   = (const float*)d_in[7];
    const float* hc2_b   = (const float*)d_in[8];
    const float* lin2_w  = (const float*)d_in[9];
    const float* lin2_b  = (const float*)d_in[10];
    const float* c1_wrel = (const float*)d_in[11];
    const float* c1_brel = (const float*)d_in[12];
    const float* c1_wroot= (const float*)d_in[13];
    const float* glin1_w = (const float*)d_in[14];
    const float* glin1_b = (const float*)d_in[15];
    const float* c2_wrel = (const float*)d_in[16];
    const float* c2_brel = (const float*)d_in[17];
    const float* c2_wroot= (const float*)d_in[18];
    const float* glin2_w = (const float*)d_in[19];
    const float* glin2_b = (const float*)d_in[20];
    const float* fc_w    = (const float*)d_in[21];
    const float* fc_b    = (const float*)d_in[22];

    // ---- workspace carve ----
    char* wsp = (char*)d_ws;
    size_t off = 0;
    auto carve = [&](size_t bytes) -> char* {
        char* p = wsp + off;
        off = (off + bytes + 255) & ~(size_t)255;
        return p;
    };
    int*   flags  = (int*)carve(16);
    int*   offs   = (int*)carve(110003 * 4);
    int*   bcur   = (int*)carve(3 * NBK * BCSTRIDE * 4);                  // 48 KB line-padded
    u16*   vals   = (u16*)carve(2400000 * 2);
    _Float16* F   = (_Float16*)carve((4 * 32768 + 8192) * 2);             // frag-ordered weights
    unsigned* pairs = (unsigned*)carve((size_t)3 * NBK * BKCAP * 4);      // 12.6 MB
    _Float16* P  = (_Float16*)carve((size_t)NN * 128 * 2);                // 12.8 MB
    _Float16* L  = (_Float16*)carve((size_t)NN * 128 * 2);                // 12.8 MB
    _Float16* MH = (_Float16*)carve((size_t)HECNT * 128 * 2);             // 2.56 MB
    _Float16* XA = (_Float16*)carve((size_t)NN * 128 * 2);                // 12.8 MB

    float* XO = (float*)d_out;                 // final X: 50000 x 128 f32
    float* YO = XO + (size_t)NN * 128;         // final y: 50000 x 64 f32

    const half8* F0 = (const half8*)F;                     // L1 [hc1|lin1]
    const half8* F1 = (const half8*)(F + 32768);           // L2
    const half8* F2 = (const half8*)(F + 2 * 32768);       // L3
    const half8* F3 = (const half8*)(F + 3 * 32768);       // L4
    const half8* F4 = (const half8*)(F + 4 * 32768);       // fc

    const int* offs_he   = offs;                    // [HECNT+1]
    const int* offs_node = offs + HECNT + 1;        // [NN+1]
    const int* offs_dst  = offs + HECNT + NN + 2;   // [NN+1]
    const u16* vals_he   = vals;
    const u16* vals_node = vals + 800000;
    const u16* vals_dst  = vals + 1600000;

    int g64 = (NN + 63) / 64;         // 782
    int ghe = (HECNT + 3) / 4;        // 2500
    int gnn = (NN + 3) / 4;           // 12500

    // 1. weight prep + detect + bucket cursor init
    prep_k<<<dim3(16, 6), 256, 0, stream>>>(EIX, HIX, flags, bcur,
                                            hc1_w, lin1_w, hc2_w, lin2_w,
                                            c1_wrel, c1_wroot, glin1_w,
                                            c2_wrel, c2_wroot, glin2_w, fc_w, F);
    // 2. bin (196 HIX-dual + 196 EIX blocks) || L1 GEMM (782 blocks)
    phase1_k<<<2 * BIN_GRID + g64, 256, 0, stream>>>(EIX, HIX, flags, bcur, pairs,
                                                     X, F0, lin1_b, P, L);
    // 3. CSR finish
    bfin2_k<<<3 * NBK, 256, 0, stream>>>(bcur, pairs, offs, vals);

    // ---- Layer 1: X1 = leaky(Dinv H Binv H^T (X@hc1) + hc1_b + X@lin1 + lin1_b) ----
    gather_k<<<ghe, 256, 0, stream>>>(offs_he, vals_he, P, MH, HECNT, NN, 1, nullptr, nullptr, 0);
    gather_k<<<gnn, 256, 0, stream>>>(offs_node, vals_node, MH, XA, NN, HECNT, 1, hc1_b, L, 1);

    // ---- Layer 2 ----
    gemm2h_k<<<g64, 256, 0, stream>>>(XA, F1, lin2_b, P, L, NN);
    gather_k<<<ghe, 256, 0, stream>>>(offs_he, vals_he, P, MH, HECNT, NN, 1, nullptr, nullptr, 0);
    gather_k<<<gnn, 256, 0, stream>>>(offs_node, vals_node, MH, XA, NN, HECNT, 1, hc2_b, L, 1);   // XA = X2

    // ---- Layer 3: X3 = leaky([AGG|X2] @ [Wrel; Wroot+glin1] + brel + glin1_b) ----
    gather_k<<<gnn, 256, 0, stream>>>(offs_dst, vals_dst, XA, P, NN, NN, 0, nullptr, nullptr, 0); // P = AGG
    gemmk2_k<0><<<g64, 256, 0, stream>>>(P, XA, F2, c1_brel, glin1_b,
                                         nullptr, XA, nullptr, nullptr, nullptr, NN);             // XA = X3

    // ---- Layer 4 + fc head fused: AGG(X3) -> [AGG|X3] @ F3 -> XO (f32); X4 tile -> fc -> YO ----
    gather_k<<<gnn, 256, 0, stream>>>(offs_dst, vals_dst, XA, P, NN, NN, 0, nullptr, nullptr, 0);
    gemmk2_k<1><<<g64, 256, 0, stream>>>(P, XA, F3, c2_brel, glin2_b,
                                         XO, nullptr, F4, fc_b, YO, NN);
}